// Round 3
// baseline (7299.835 us; speedup 1.0000x reference)
//
#include <hip/hip_runtime.h>

// ---------------------------------------------------------------------------
// 2-layer GRU (B=64,T=1024,D=256,H=512) + dense head, persistent-RNN style.
// v4 = verified 64-wg sc1/agent exchange protocol (unchanged) + batched
// fragment loads.
//   Root cause of 9.1us/step: legacy did 16 (L0) / 32 (L1) __hip_atomic_load
//   fragment loads PER STEP inside the MFMA loop; LLVM serializes atomic
//   loads -> 16-32 x ~900cy MALL round-trips per step. Atomicity is not
//   needed (data is quiescent once the flag is seen) -- only sc1 visibility.
//   v4 issues all fragment loads up-front as plain sc1 asm loads, then one
//   s_waitcnt vmcnt(0) + sched_barrier (rule #18) before the MFMA loop.
//   L0: 16 h-loads up-front, x-side MFMAs overlap the load latency.
//   L1: two phases of 8 (h,y) pairs (VGPR budget).
//   Exchange protocol, buffers, epochs, stores: bit-identical to the
//   harness-verified baseline. Watchdog on the barrier poll -> hang-proof.
// ---------------------------------------------------------------------------

#define T_STEPS 1024
#define NWG_L0  32
#define NWG_TOT 64

typedef _Float16 f16x8 __attribute__((ext_vector_type(8)));
typedef float    f32x4 __attribute__((ext_vector_type(4)));

// ws layout (bytes) -- identical to verified baseline
#define H0_OFF   0
#define H1_OFF   131072
#define Y0_OFF   262144
#define FLAG_OFF 393216
#define FSTRIDE  32          // flag stride in u32 (128 B)

#define BUD_BAR  (1ull << 22)   // ~1.7ms @2.4GHz watchdog budget per barrier

#define WAITV0()   asm volatile("s_waitcnt vmcnt(0)")
#define SB()       __builtin_amdgcn_sched_barrier(0)
#define FENCE_VM() asm volatile("s_waitcnt vmcnt(0)" ::: "memory")

__device__ __forceinline__ float sigm_f(float x) { return 1.0f / (1.0f + __expf(-x)); }
__device__ __forceinline__ float tanh_f(float x) { return 2.0f / (1.0f + __expf(-2.0f * x)) - 1.0f; }

__device__ __forceinline__ f32x4 mfma16(f16x8 a, f16x8 b, f32x4 c) {
    return __builtin_amdgcn_mfma_f32_16x16x32_f16(a, b, c, 0, 0, 0);
}

__device__ __forceinline__ f16x8 pack8(const float* __restrict__ src, int stride) {
    f16x8 r;
#pragma unroll
    for (int j = 0; j < 8; ++j) r[j] = (_Float16)src[j * stride];
    return r;
}

// sc1 (device-coherent) 16B fragment load, NOT waited -- counted by caller.
// Same path as the verified __hip_atomic_load(AGENT) (global_load ... sc1),
// minus compiler serialization. Atomicity not required: data is quiescent.
__device__ __forceinline__ f16x8 ld_frag_a(const _Float16* p) {
    f16x8 v;
    asm volatile("global_load_dwordx4 %0, %1, off sc1" : "=v"(v) : "v"(p));
    return v;
}

// sc1 f16 store (verified)
__device__ __forceinline__ void st_dev_f16(_Float16* p, float v) {
    unsigned short b = __builtin_bit_cast(unsigned short, (_Float16)v);
    __hip_atomic_store((unsigned short*)p, b, __ATOMIC_RELAXED, __HIP_MEMORY_SCOPE_AGENT);
}

// arrive: drain this wave's mem ops, wg-sync, publish flag (verified)
__device__ __forceinline__ void bar_arrive(unsigned* flags, int wg, unsigned epoch) {
    asm volatile("s_waitcnt vmcnt(0)" ::: "memory");
    __syncthreads();
    if (threadIdx.x == 0)
        __hip_atomic_store(&flags[wg * FSTRIDE], epoch,
                           __ATOMIC_RELAXED, __HIP_MEMORY_SCOPE_AGENT);
}
// wait: wave0 polls all 64 flags (lane i -> flag i), watchdog'd (hang-proof)
__device__ __forceinline__ void bar_wait_wd(const unsigned* flags, unsigned epoch,
                                            int wave, int lane,
                                            volatile unsigned* s_alive) {
    if (wave == 0 && *s_alive) {
        const unsigned* p = &flags[lane * FSTRIDE];
        unsigned long long t0 = clock64();
        for (;;) {
            unsigned v = __hip_atomic_load(p, __ATOMIC_RELAXED, __HIP_MEMORY_SCOPE_AGENT);
            if (__all(v >= epoch)) break;
            if (clock64() - t0 > BUD_BAR) { if (lane == 0) *s_alive = 0; break; }
        }
    }
    __syncthreads();
    asm volatile("" ::: "memory");
}

#define BFRAG(g, kt) __builtin_bit_cast(f16x8, ldsB[((g) * 16 + (kt)) * 64 + lane])

__global__ __launch_bounds__(256, 1) void gru_scan(
    const float* __restrict__ x,     // [64,1024,256]
    const float* __restrict__ Wi0,   // [256,1536]
    const float* __restrict__ bi0,   // [1536]
    const float* __restrict__ Wh0,   // [512,1536]
    const float* __restrict__ bhn0,  // [512]
    const float* __restrict__ Wi1,   // [512,1536]
    const float* __restrict__ bi1,   // [1536]
    const float* __restrict__ Wh1,   // [512,1536]
    const float* __restrict__ bhn1,  // [512]
    float* __restrict__ c0_out,      // [64,512]
    float* __restrict__ c1_out,      // [64,512]
    unsigned char* __restrict__ ws)
{
    __shared__ uint4 ldsB[48 * 64];  // 48 KB: W_h fragments, frag idx nt*16+kt
    __shared__ unsigned s_alive;

    const int tid  = threadIdx.x;
    const int wave = tid >> 6;
    const int lane = tid & 63;
    const int quad = lane >> 4;
    const int l16  = lane & 15;
    const int wg   = blockIdx.x;
    const bool isL1 = (wg >= NWG_L0);
    const int cslice = (isL1 ? (wg - NWG_L0) : wg) * 16;

    if (tid == 0) s_alive = 1u;

    _Float16* h0buf = (_Float16*)(ws + H0_OFF);
    _Float16* h1buf = (_Float16*)(ws + H1_OFF);
    _Float16* y0buf = (_Float16*)(ws + Y0_OFF);
    unsigned* flags = (unsigned*)(ws + FLAG_OFF);

    const float* Wh = isL1 ? Wh1 : Wh0;
    const float* Wi = isL1 ? Wi1 : Wi0;

    // ---- stage W_h fragments into LDS ----
    // B-frag (16x16x32): lane holds B[k = kt*32 + quad*8 + j][n = l16]
    for (int f = wave * 12; f < wave * 12 + 12; ++f) {
        int nt = f >> 4, kt = f & 15;
        const float* src = Wh + (kt * 32 + quad * 8) * 1536 + nt * 512 + cslice + l16;
        ldsB[f * 64 + lane] = __builtin_bit_cast(uint4, pack8(src, 1536));
    }

    // ---- W_i fragments in registers ----
    f16x8 wif[48];
    if (!isL1) {
#pragma unroll
        for (int nt = 0; nt < 3; ++nt)
#pragma unroll
            for (int kt = 0; kt < 8; ++kt)
                wif[nt * 8 + kt] = pack8(Wi + (kt * 32 + quad * 8) * 1536 + nt * 512 + cslice + l16, 1536);
    } else {
#pragma unroll
        for (int nt = 0; nt < 3; ++nt)
#pragma unroll
            for (int kt = 0; kt < 16; ++kt)
                wif[nt * 16 + kt] = pack8(Wi + (kt * 32 + quad * 8) * 1536 + nt * 512 + cslice + l16, 1536);
    }

    const float* bi = isL1 ? bi1 : bi0;
    const float* bh = isL1 ? bhn1 : bhn0;
    const float bi_r = bi[cslice + l16];
    const float bi_z = bi[512 + cslice + l16];
    const float bi_n = bi[1024 + cslice + l16];
    const float bhn  = bh[cslice + l16];

    __syncthreads();

    float hstate[4] = {0.f, 0.f, 0.f, 0.f};
    const int rowA = wave * 16 + l16;
    const int rowC = wave * 16 + quad * 4;
    const int cu   = cslice + l16;
    const f32x4 z4 = {0.f, 0.f, 0.f, 0.f};

    for (int s = 0; s < T_STEPS + 1; ++s) {
        const int pr = s & 1;

        // --- prefetch x for this step (overlaps the barrier wait) ---
        f32x4 xr[16];
        if (!isL1 && s < T_STEPS) {
            const float* px = x + (size_t)rowA * 262144 + s * 256 + quad * 8;
#pragma unroll
            for (int kt = 0; kt < 8; ++kt) {
                xr[kt * 2]     = *(const f32x4*)(px + kt * 32);
                xr[kt * 2 + 1] = *(const f32x4*)(px + kt * 32 + 4);
            }
        }

        if (s > 0) bar_wait_wd(flags, (unsigned)s, wave, lane, &s_alive);

        if (!isL1 && s < T_STEPS) {
            const _Float16* hR = h0buf + pr * 32768;
            _Float16* hW = h0buf + (pr ^ 1) * 32768;
            _Float16* yW = y0buf + (pr ^ 1) * 32768;

            // All waves at vmcnt-clean point; x loads certainly complete.
            FENCE_VM();

            // convert x -> f16 A-fragments BEFORE issuing asm loads, so any
            // compiler-inserted wait for xr cannot drain our counted loads
            f16x8 axf[8];
#pragma unroll
            for (int kt = 0; kt < 8; ++kt) {
                f32x4 x0 = xr[kt * 2], x1 = xr[kt * 2 + 1];
                f16x8 a;
                a[0] = (_Float16)x0[0]; a[1] = (_Float16)x0[1];
                a[2] = (_Float16)x0[2]; a[3] = (_Float16)x0[3];
                a[4] = (_Float16)x1[0]; a[5] = (_Float16)x1[1];
                a[6] = (_Float16)x1[2]; a[7] = (_Float16)x1[3];
                axf[kt] = a;
            }
            SB();

            // issue ALL 16 h-fragment loads up-front (pipelined in MALL)
            f16x8 hb[16];
#pragma unroll
            for (int p = 0; p < 16; ++p)
                hb[p] = ld_frag_a(hR + rowA * 512 + p * 32 + quad * 8);

            // x-side MFMAs overlap the load round-trip (register-only)
            f32x4 ax0 = z4, ax1 = z4, ax2 = z4;
#pragma unroll
            for (int kt = 0; kt < 8; ++kt) {
                ax0 = mfma16(axf[kt], wif[0 * 8 + kt], ax0);
                ax1 = mfma16(axf[kt], wif[1 * 8 + kt], ax1);
                ax2 = mfma16(axf[kt], wif[2 * 8 + kt], ax2);
            }

            SB(); WAITV0(); SB();   // all 16 h frags in regs (rule #18 fence)

            f32x4 ah0 = z4, ah1 = z4, ah2 = z4;
#pragma unroll
            for (int kt = 0; kt < 16; ++kt) {
                f16x8 a = hb[kt];
                ah0 = mfma16(a, BFRAG(0, kt), ah0);
                ah1 = mfma16(a, BFRAG(1, kt), ah1);
                ah2 = mfma16(a, BFRAG(2, kt), ah2);
            }

#pragma unroll
            for (int i = 0; i < 4; ++i) {
                const int b = rowC + i;
                float r = sigm_f(ax0[i] + bi_r + ah0[i]);
                float z = sigm_f(ax1[i] + bi_z + ah1[i]);
                float n = tanh_f(ax2[i] + bi_n + r * (ah2[i] + bhn));
                float hnew = (1.0f - z) * n + z * hstate[i];
                hstate[i] = hnew;
                st_dev_f16(&hW[b * 512 + cu], hnew);
                st_dev_f16(&yW[b * 512 + cu], tanh_f(hnew));
                if (s == T_STEPS - 1) c0_out[b * 512 + cu] = hnew;
            }
        }

        if (isL1 && s >= 1) {
            const _Float16* hR = h1buf + pr * 32768;
            _Float16* hW = h1buf + (pr ^ 1) * 32768;
            const _Float16* yR = y0buf + pr * 32768;  // y0 from global step s-1

            FENCE_VM();
            SB();

            // phase A: issue 8 (h,y) pairs up-front
            f16x8 hb[8], yb[8];
#pragma unroll
            for (int p = 0; p < 8; ++p) {
                hb[p] = ld_frag_a(hR + rowA * 512 + p * 32 + quad * 8);
                yb[p] = ld_frag_a(yR + rowA * 512 + p * 32 + quad * 8);
            }

            SB(); WAITV0(); SB();   // pairs 0..7 in regs

            f32x4 ah0 = z4, ah1 = z4, ah2 = z4, ax0 = z4, ax1 = z4, ax2 = z4;
#pragma unroll
            for (int kt = 0; kt < 8; ++kt) {
                f16x8 ah = hb[kt], ay = yb[kt];
                ah0 = mfma16(ah, BFRAG(0, kt), ah0);
                ah1 = mfma16(ah, BFRAG(1, kt), ah1);
                ah2 = mfma16(ah, BFRAG(2, kt), ah2);
                ax0 = mfma16(ay, wif[0 * 16 + kt], ax0);
                ax1 = mfma16(ay, wif[1 * 16 + kt], ax1);
                ax2 = mfma16(ay, wif[2 * 16 + kt], ax2);
                // refill slot kt with pair kt+8 (phase B), overlaps compute
                hb[kt] = ld_frag_a(hR + rowA * 512 + (kt + 8) * 32 + quad * 8);
                yb[kt] = ld_frag_a(yR + rowA * 512 + (kt + 8) * 32 + quad * 8);
            }

            SB(); WAITV0(); SB();   // pairs 8..15 in regs

#pragma unroll
            for (int kt = 8; kt < 16; ++kt) {
                f16x8 ah = hb[kt - 8], ay = yb[kt - 8];
                ah0 = mfma16(ah, BFRAG(0, kt), ah0);
                ah1 = mfma16(ah, BFRAG(1, kt), ah1);
                ah2 = mfma16(ah, BFRAG(2, kt), ah2);
                ax0 = mfma16(ay, wif[0 * 16 + kt], ax0);
                ax1 = mfma16(ay, wif[1 * 16 + kt], ax1);
                ax2 = mfma16(ay, wif[2 * 16 + kt], ax2);
            }

#pragma unroll
            for (int i = 0; i < 4; ++i) {
                const int b = rowC + i;
                float r = sigm_f(ax0[i] + bi_r + ah0[i]);
                float z = sigm_f(ax1[i] + bi_z + ah1[i]);
                float n = tanh_f(ax2[i] + bi_n + r * (ah2[i] + bhn));
                float hnew = (1.0f - z) * n + z * hstate[i];
                hstate[i] = hnew;
                st_dev_f16(&hW[b * 512 + cu], hnew);
                if (s == T_STEPS) c1_out[b * 512 + cu] = hnew;
            }
        }

        if (s < T_STEPS) bar_arrive(flags, wg, (unsigned)(s + 1));
    }
}

// out = tanh(tanh(c1) @ W_out + b_out) : [64,512] @ [512,512], fp32
__global__ __launch_bounds__(256) void dense_out(
    const float* __restrict__ c1, const float* __restrict__ Wout,
    const float* __restrict__ bout, float* __restrict__ out)
{
    __shared__ float a[512];
    const int b = blockIdx.x, tid = threadIdx.x;
    a[tid]       = tanh_f(c1[b * 512 + tid]);
    a[tid + 256] = tanh_f(c1[b * 512 + tid + 256]);
    __syncthreads();
    float acc0 = 0.f, acc1 = 0.f;
#pragma unroll 4
    for (int k = 0; k < 512; ++k) {
        const float av = a[k];
        acc0 += av * Wout[k * 512 + tid];
        acc1 += av * Wout[k * 512 + tid + 256];
    }
    out[b * 512 + tid]       = tanh_f(acc0 + bout[tid]);
    out[b * 512 + tid + 256] = tanh_f(acc1 + bout[tid + 256]);
}

extern "C" void kernel_launch(void* const* d_in, const int* in_sizes, int n_in,
                              void* d_out, int out_size, void* d_ws, size_t ws_size,
                              hipStream_t stream)
{
    const float* x    = (const float*)d_in[0];
    const float* Wi0  = (const float*)d_in[1];
    const float* bi0  = (const float*)d_in[2];
    const float* Wh0  = (const float*)d_in[3];
    const float* bhn0 = (const float*)d_in[4];
    const float* Wi1  = (const float*)d_in[5];
    const float* bi1  = (const float*)d_in[6];
    const float* Wh1  = (const float*)d_in[7];
    const float* bhn1 = (const float*)d_in[8];
    const float* Wout = (const float*)d_in[9];
    const float* bout = (const float*)d_in[10];
    float* out = (float*)d_out;
    unsigned char* ws = (unsigned char*)d_ws;

    // zero h/y double buffers + flag array (ws poisoned 0xAA each launch)
    hipMemsetAsync(ws, 0, FLAG_OFF + 8192, stream);

    gru_scan<<<NWG_TOT, 256, 0, stream>>>(x, Wi0, bi0, Wh0, bhn0,
                                          Wi1, bi1, Wh1, bhn1,
                                          out + 32768, out + 65536, ws);
    dense_out<<<64, 256, 0, stream>>>(out + 65536, Wout, bout, out);
}